// Round 6
// baseline (66.020 us; speedup 1.0000x reference)
//
#include <hip/hip_runtime.h>
#include <hip/hip_bf16.h>
#include <math.h>

#define BB 4
#define CC 64
#define HID 32
#define NN 4096
#define LOG2E 1.44269504088896f

typedef short sh2 __attribute__((ext_vector_type(2)));
typedef short sh8 __attribute__((ext_vector_type(8)));
typedef float f2v __attribute__((ext_vector_type(2)));
typedef float f4v __attribute__((ext_vector_type(4)));

#define MFMA32(A,B,C) __builtin_amdgcn_mfma_f32_16x16x32_bf16(A,B,C,0,0,0)

__device__ __forceinline__ short f2b(float f) {
    __hip_bfloat16 h = __float2bfloat16(f);
    union { __hip_bfloat16 hb; short s; } u; u.hb = h; return u.s;
}

__device__ __forceinline__ void gload_lds16(const short* g, short* l) {
    __builtin_amdgcn_global_load_lds(
        (const __attribute__((address_space(1))) unsigned int*)g,
        (__attribute__((address_space(3))) unsigned int*)l, 16, 0, 0);
}

// ---------------------------------------------------------------------------
// Kernel A: QKV projection -> bf16 Q[n][32] (pre-scaled by log2(e)),
// K[n][32], Vtp[32][n-permuted].  pos(key%32) = 8*((k>>2)&3)+(k&3)+4*(k>>4).
// ---------------------------------------------------------------------------
__global__ __launch_bounds__(1024) void qkv_kernel(
    const float* __restrict__ x,
    const float* __restrict__ wq, const float* __restrict__ bq,
    const float* __restrict__ wk, const float* __restrict__ bk,
    const float* __restrict__ wv, const float* __restrict__ bv,
    short* __restrict__ Qw, short* __restrict__ Kw, short* __restrict__ Vtp)
{
    __shared__ float xs[64][80];
    __shared__ float ws[96][80];
    __shared__ float bs[96];

    const int t  = threadIdx.x;
    const int b  = blockIdx.x >> 6;
    const int n0 = (blockIdx.x & 63) << 6;

    {
        int c = t >> 4, j4 = (t & 15) << 2;
        *(f4v*)&xs[c][j4] = *(const f4v*)(x + ((size_t)(b*CC + c))*NN + n0 + j4);
    }
    #pragma unroll
    for (int kl = 0; kl < 2; ++kl) {
        int idx = t + 1024*kl;
        if (idx < 1536) {
            int r = idx >> 4, c4 = (idx & 15) << 2;
            const float* src = (r < 32) ? (wq + r*CC + c4)
                             : (r < 64) ? (wk + (r-32)*CC + c4)
                                        : (wv + (r-64)*CC + c4);
            *(f4v*)&ws[r][c4] = *(const f4v*)src;
        }
    }
    if (t < 96) bs[t] = (t < 32) ? bq[t] : (t < 64) ? bk[t-32] : bv[t-64];
    __syncthreads();

    const int hg = t & 31;
    const int j0 = (t >> 5) << 1;   // 2 spatial cols per thread

    float aq[2], ak[2], av[2];
    #pragma unroll
    for (int jj = 0; jj < 2; ++jj) { aq[jj]=bs[hg]; ak[jj]=bs[32+hg]; av[jj]=bs[64+hg]; }

    #pragma unroll
    for (int cs = 0; cs < 16; ++cs) {
        f4v wqv = *(f4v*)&ws[hg][cs*4];
        f4v wkv = *(f4v*)&ws[32+hg][cs*4];
        f4v wvv = *(f4v*)&ws[64+hg][cs*4];
        #pragma unroll
        for (int cc = 0; cc < 4; ++cc) {
            f2v xv = *(f2v*)&xs[cs*4+cc][j0];
            #pragma unroll
            for (int jj = 0; jj < 2; ++jj) {
                aq[jj] += wqv[cc]*xv[jj];
                ak[jj] += wkv[cc]*xv[jj];
                av[jj] += wvv[cc]*xv[jj];
            }
        }
    }

    const size_t nbase = (size_t)b*NN + n0 + j0;
    #pragma unroll
    for (int jj = 0; jj < 2; ++jj) {
        Qw[(nbase + jj)*HID + hg] = f2b(aq[jj] * LOG2E);  // exp2 trick
        Kw[(nbase + jj)*HID + hg] = f2b(ak[jj]);
    }
    const int w0  = j0 & 31;
    const int pos = 8*((w0 >> 2) & 3) + (w0 & 3) + 4*(w0 >> 4);
    sh2 vv; vv[0] = f2b(av[0]); vv[1] = f2b(av[1]);
    *(sh2*)(Vtp + ((size_t)b*HID + hg)*NN + n0 + (j0 & ~31) + pos) = vv;
}

// ---------------------------------------------------------------------------
// Kernel B: flash attention partials.  Grid (BB*32)<<LKQ blocks x 512 thr.
// Block = (batch, 128-q tile, key 1/NKQ).  8 waves x 16 q each; K/V tiles
// of 64 keys double-buffered in LDS via global_load_lds (pre-swizzled
// source, swizzled read).  Writes f32 z[q][32], l[q] partials.
// ---------------------------------------------------------------------------
template<int LKQ>
__global__ __launch_bounds__(512, 4) void attn_kernel(
    const short* __restrict__ Qw, const short* __restrict__ Kw,
    const short* __restrict__ Vtp,
    float* __restrict__ zws, float* __restrict__ lws)
{
    constexpr int NKQ  = 1 << LKQ;
    constexpr int KEYS = NN >> LKQ;
    constexpr int NT   = KEYS / 64;

    __shared__ short Kb[2][2048];   // [buf][64 keys x 32 dims] swizzled
    __shared__ short Vb[2][2048];   // [buf][32 d x 64 keys] swizzled

    const int t    = threadIdx.x;
    const int blk  = blockIdx.x;
    const int kq   = blk & (NKQ - 1);
    const int qb   = (blk >> LKQ) & 31;
    const int b    = blk >> (LKQ + 5);
    const int q0   = qb << 7;
    const int k0   = kq * KEYS;
    const int lane = t & 63;
    const int w    = t >> 6;
    const int g    = lane >> 4;
    const int qi   = lane & 15;

    // Q B-fragment (16 q rows of this wave)
    const sh8 qf = *(const sh8*)(Qw + ((size_t)b*NN + q0 + w*16 + qi)*HID + 8*g);

    // staging: lanes of waves 0-3 copy K tile (4KB), waves 4-7 copy V tile.
    const int i    = (w & 3)*64 + lane;          // 0..255
    const int kk   = i >> 2;
    const int sigk = (kk + (kk >> 2)) & 3;
    const int ku   = (i & 3) ^ sigk;             // dim-slice to fetch
    const short* ksrc = Kw + ((size_t)b*NN + k0 + kk)*HID + ku*8;
    const int vd   = i >> 3;
    const int vu   = (i & 7) ^ (vd & 7);         // key-slice to fetch
    const short* vsrc = Vtp + ((size_t)b*HID + vd)*NN + k0 + vu*8;

    // per-lane LDS read offsets (shorts, relative to buffer base)
    int krd[2][2], vrd[2][2];
    #pragma unroll
    for (int G = 0; G < 2; ++G) {
        #pragma unroll
        for (int h = 0; h < 2; ++h) {
            int kr = G*32 + h*16 + qi;
            int sg = (kr + (kr >> 2)) & 3;
            krd[G][h] = kr*32 + ((g ^ sg) << 3);
            int d  = h*16 + qi;
            vrd[G][h] = d*64 + (((4*G + g) ^ (d & 7)) << 3);
        }
    }

    const f4v zf = {0.f,0.f,0.f,0.f};
    f4v z0 = zf, z1 = zf;
    float lacc = 0.f;

    if (w < 4) gload_lds16(ksrc, &Kb[0][(w & 3)*512]);
    else       gload_lds16(vsrc, &Vb[0][(w & 3)*512]);
    __syncthreads();

    for (int tt = 0; tt < NT; ++tt) {
        const int cur = tt & 1;
        if (tt + 1 < NT) {
            if (w < 4) gload_lds16(ksrc + (size_t)(tt+1)*64*HID, &Kb[cur^1][(w & 3)*512]);
            else       gload_lds16(vsrc + (tt+1)*64,             &Vb[cur^1][(w & 3)*512]);
        }
        const short* KbC = &Kb[cur][0];
        const short* VbC = &Vb[cur][0];
        #pragma unroll
        for (int G = 0; G < 2; ++G) {
            sh8 a0 = *(const sh8*)(KbC + krd[G][0]);
            sh8 a1 = *(const sh8*)(KbC + krd[G][1]);
            sh8 v0 = *(const sh8*)(VbC + vrd[G][0]);
            sh8 v1 = *(const sh8*)(VbC + vrd[G][1]);
            f4v s0 = MFMA32(a0, qf, zf);
            f4v s1 = MFMA32(a1, qf, zf);
            float e[8];
            e[0]=__builtin_amdgcn_exp2f(s0[0]); e[1]=__builtin_amdgcn_exp2f(s0[1]);
            e[2]=__builtin_amdgcn_exp2f(s0[2]); e[3]=__builtin_amdgcn_exp2f(s0[3]);
            e[4]=__builtin_amdgcn_exp2f(s1[0]); e[5]=__builtin_amdgcn_exp2f(s1[1]);
            e[6]=__builtin_amdgcn_exp2f(s1[2]); e[7]=__builtin_amdgcn_exp2f(s1[3]);
            lacc += ((e[0]+e[1])+(e[2]+e[3])) + ((e[4]+e[5])+(e[6]+e[7]));
            sh8 p;
            p[0]=f2b(e[0]); p[1]=f2b(e[1]); p[2]=f2b(e[2]); p[3]=f2b(e[3]);
            p[4]=f2b(e[4]); p[5]=f2b(e[5]); p[6]=f2b(e[6]); p[7]=f2b(e[7]);
            z0 = MFMA32(v0, p, z0);   // d 0-15
            z1 = MFMA32(v1, p, z1);   // d 16-31
        }
        __syncthreads();
    }

    // full denominator for column qi of this wave's q-tile
    lacc += __shfl_xor(lacc, 16, 64);
    lacc += __shfl_xor(lacc, 32, 64);

    const int q = q0 + w*16 + qi;
    float* zb = zws + ((size_t)(b*NKQ + kq)*HID)*NN + q;
    #pragma unroll
    for (int r = 0; r < 4; ++r) {
        zb[(size_t)(4*g + r)*NN]      = z0[r];
        zb[(size_t)(16 + 4*g + r)*NN] = z1[r];
    }
    if (lane < 16) lws[((size_t)(b*NKQ + kq))*NN + q0 + w*16 + lane] = lacc;
}

// ---------------------------------------------------------------------------
// Kernel C: merge partials + wp projection (f32) + bias + residual.
// 256 blocks x 256 thr; block = (batch, 64-col tile); thread = (n, 16 c's).
// ---------------------------------------------------------------------------
template<int LKQ>
__global__ __launch_bounds__(256) void merge_kernel(
    const float* __restrict__ zws, const float* __restrict__ lws,
    const float* __restrict__ x, const float* __restrict__ wp,
    const float* __restrict__ bp, float* __restrict__ out)
{
    constexpr int NKQ = 1 << LKQ;
    __shared__ float wps[CC][HID+1];
    __shared__ float bps[CC];

    const int t  = threadIdx.x;
    const int b  = blockIdx.x >> 6;
    const int n0 = (blockIdx.x & 63) << 6;

    for (int i = t; i < CC*HID; i += 256) wps[i >> 5][i & 31] = wp[i];
    if (t < CC) bps[t] = bp[t];
    __syncthreads();

    const int n  = n0 + (t & 63);
    const int cg = t >> 6;   // 0..3 -> 16 channels each

    float l = 0.f;
    #pragma unroll
    for (int kq = 0; kq < NKQ; ++kq)
        l += lws[((size_t)(b*NKQ + kq))*NN + n];
    const float inv = 1.f / l;

    float zn[HID];
    #pragma unroll
    for (int d = 0; d < HID; ++d) {
        float s = 0.f;
        #pragma unroll
        for (int kq = 0; kq < NKQ; ++kq)
            s += zws[((size_t)(b*NKQ + kq)*HID + d)*NN + n];
        zn[d] = s * inv;
    }

    #pragma unroll
    for (int cc = 0; cc < 16; ++cc) {
        const int c = cg*16 + cc;
        float acc = bps[c];
        #pragma unroll
        for (int d = 0; d < HID; ++d) acc += wps[c][d] * zn[d];
        const size_t gi = ((size_t)(b*CC + c))*NN + n;
        out[gi] = x[gi] + acc;
    }
}

extern "C" void kernel_launch(void* const* d_in, const int* in_sizes, int n_in,
                              void* d_out, int out_size, void* d_ws, size_t ws_size,
                              hipStream_t stream) {
    const float* x  = (const float*)d_in[0];
    const float* wq = (const float*)d_in[1];
    const float* bq = (const float*)d_in[2];
    const float* wk = (const float*)d_in[3];
    const float* bk = (const float*)d_in[4];
    const float* wv = (const float*)d_in[5];
    const float* bv = (const float*)d_in[6];
    const float* wp = (const float*)d_in[7];
    const float* bp = (const float*)d_in[8];
    float* out = (float*)d_out;

    short* Qw  = (short*)d_ws;
    short* Kw  = Qw + (size_t)BB*NN*HID;
    short* Vtp = Kw + (size_t)BB*NN*HID;
    float* zws = (float*)(Vtp + (size_t)BB*NN*HID);
    const size_t qkvB = (size_t)3*BB*NN*HID*2;

    // pick largest key-split that fits the workspace
    int LKQ = 2;
    while (LKQ > 0) {
        size_t need = qkvB + ((size_t)(BB << LKQ))*HID*NN*4
                           + ((size_t)(BB << LKQ))*NN*4;
        if (need <= ws_size) break;
        --LKQ;
    }

    qkv_kernel<<<dim3(256), dim3(1024), 0, stream>>>(x, wq, bq, wk, bk, wv, bv, Qw, Kw, Vtp);

    if (LKQ == 2) {
        float* lws = zws + (size_t)(BB << 2)*HID*NN;
        attn_kernel<2><<<dim3((BB*32) << 2), dim3(512), 0, stream>>>(Qw, Kw, Vtp, zws, lws);
        merge_kernel<2><<<dim3(256), dim3(256), 0, stream>>>(zws, lws, x, wp, bp, out);
    } else if (LKQ == 1) {
        float* lws = zws + (size_t)(BB << 1)*HID*NN;
        attn_kernel<1><<<dim3((BB*32) << 1), dim3(512), 0, stream>>>(Qw, Kw, Vtp, zws, lws);
        merge_kernel<1><<<dim3(256), dim3(256), 0, stream>>>(zws, lws, x, wp, bp, out);
    } else {
        float* lws = zws + (size_t)BB*HID*NN;
        attn_kernel<0><<<dim3(BB*32), dim3(512), 0, stream>>>(Qw, Kw, Vtp, zws, lws);
        merge_kernel<0><<<dim3(256), dim3(256), 0, stream>>>(zws, lws, x, wp, bp, out);
    }
}

// Round 7
// 30.136 us; speedup vs baseline: 2.1908x; 2.1908x over previous
//
#include <hip/hip_runtime.h>
#include <hip/hip_bf16.h>
#include <math.h>

#define BB 4
#define CC 64
#define HID 32
#define NN 4096
#define LOG2E 1.44269504088896f

typedef short sh2 __attribute__((ext_vector_type(2)));
typedef short sh8 __attribute__((ext_vector_type(8)));
typedef float f2v __attribute__((ext_vector_type(2)));
typedef float f4v __attribute__((ext_vector_type(4)));

#define MFMA32(A,B,C) __builtin_amdgcn_mfma_f32_16x16x32_bf16(A,B,C,0,0,0)

__device__ __forceinline__ short f2b(float f) {
    __hip_bfloat16 h = __float2bfloat16(f);
    union { __hip_bfloat16 hb; short s; } u; u.hb = h; return u.s;
}

// ---------------------------------------------------------------------------
// Kernel A: QKV projection -> bf16 Q[n][32] (pre-scaled by log2(e)),
// K[n][32], Vtp[32][n-permuted].  pos(key%32) = 8*((k>>2)&3)+(k&3)+4*(k>>4).
// Pad 84: ws-row bank stride 20 mod 32 -> 8 distinct bank-quads (was 2 at
// pad 80 = 16-way conflict on every b128 w-read).
// ---------------------------------------------------------------------------
__global__ __launch_bounds__(1024) void qkv_kernel(
    const float* __restrict__ x,
    const float* __restrict__ wq, const float* __restrict__ bq,
    const float* __restrict__ wk, const float* __restrict__ bk,
    const float* __restrict__ wv, const float* __restrict__ bv,
    short* __restrict__ Qw, short* __restrict__ Kw, short* __restrict__ Vtp)
{
    __shared__ float xs[64][84];
    __shared__ float ws[96][84];
    __shared__ float bs[96];

    const int t  = threadIdx.x;
    const int b  = blockIdx.x >> 6;
    const int n0 = (blockIdx.x & 63) << 6;

    {
        int c = t >> 4, j4 = (t & 15) << 2;
        *(f4v*)&xs[c][j4] = *(const f4v*)(x + ((size_t)(b*CC + c))*NN + n0 + j4);
    }
    #pragma unroll
    for (int kl = 0; kl < 2; ++kl) {
        int idx = t + 1024*kl;
        if (idx < 1536) {
            int r = idx >> 4, c4 = (idx & 15) << 2;
            const float* src = (r < 32) ? (wq + r*CC + c4)
                             : (r < 64) ? (wk + (r-32)*CC + c4)
                                        : (wv + (r-64)*CC + c4);
            *(f4v*)&ws[r][c4] = *(const f4v*)src;
        }
    }
    if (t < 96) bs[t] = (t < 32) ? bq[t] : (t < 64) ? bk[t-32] : bv[t-64];
    __syncthreads();

    const int hg = t & 31;
    const int j0 = (t >> 5) << 1;   // 2 spatial cols per thread

    float aq[2], ak[2], av[2];
    #pragma unroll
    for (int jj = 0; jj < 2; ++jj) { aq[jj]=bs[hg]; ak[jj]=bs[32+hg]; av[jj]=bs[64+hg]; }

    #pragma unroll
    for (int cs = 0; cs < 16; ++cs) {
        f4v wqv = *(f4v*)&ws[hg][cs*4];
        f4v wkv = *(f4v*)&ws[32+hg][cs*4];
        f4v wvv = *(f4v*)&ws[64+hg][cs*4];
        #pragma unroll
        for (int cc = 0; cc < 4; ++cc) {
            f2v xv = *(f2v*)&xs[cs*4+cc][j0];
            #pragma unroll
            for (int jj = 0; jj < 2; ++jj) {
                aq[jj] += wqv[cc]*xv[jj];
                ak[jj] += wkv[cc]*xv[jj];
                av[jj] += wvv[cc]*xv[jj];
            }
        }
    }

    const size_t nbase = (size_t)b*NN + n0 + j0;
    #pragma unroll
    for (int jj = 0; jj < 2; ++jj) {
        Qw[(nbase + jj)*HID + hg] = f2b(aq[jj] * LOG2E);  // exp2 trick
        Kw[(nbase + jj)*HID + hg] = f2b(ak[jj]);
    }
    const int w0  = j0 & 31;
    const int pos = 8*((w0 >> 2) & 3) + (w0 & 3) + 4*(w0 >> 4);
    sh2 vv; vv[0] = f2b(av[0]); vv[1] = f2b(av[1]);
    *(sh2*)(Vtp + ((size_t)b*HID + hg)*NN + n0 + (j0 & ~31) + pos) = vv;
}

// ---------------------------------------------------------------------------
// Kernel B: MFMA flash attention + projection + residual.  Single kernel.
// 256 blocks x 1024 thr (16 waves).  Block = 64 q; wave = 4 Q-frags x one
// key-sixteenth (256 keys, 8 iters of 32 keys).  4 waves/SIMD.
// 3-stage LDS merge: waves 8-15 write, 0-7 RMW, 0-3 finalize + project.
// ---------------------------------------------------------------------------
__global__ __launch_bounds__(1024, 4) void attn_kernel(
    const short* __restrict__ Qw, const short* __restrict__ Kw,
    const short* __restrict__ Vtp, const float* __restrict__ x,
    const float* __restrict__ wp, const float* __restrict__ bp,
    float* __restrict__ out)
{
    __shared__ float zr[8][64][33];   // [slot][q][d]  (67.6 KB)
    __shared__ float lr[8][64];

    const int t    = threadIdx.x;
    const int b    = blockIdx.x >> 6;
    const int q0   = (blockIdx.x & 63) << 6;
    const int lane = t & 63;
    const int w    = t >> 6;        // 0..15: key-sixteenth
    const int g    = lane >> 4;
    const int qi   = lane & 15;

    // 4 Q B-fragments, k-order dims 8g..8g+7
    sh8 qf[4];
    #pragma unroll
    for (int S = 0; S < 4; ++S)
        qf[S] = *(const sh8*)(Qw + ((size_t)b*NN + q0 + S*16 + qi)*HID + 8*g);

    const short* kp = Kw  + ((size_t)b*NN  + w*256 + qi)*HID + 8*g;
    const short* vp = Vtp + ((size_t)b*HID + qi)*NN + w*256 + 8*g;

    const f4v zf = {0.f,0.f,0.f,0.f};
    f4v z0[4], z1[4];
    float lacc[4];
    #pragma unroll
    for (int S = 0; S < 4; ++S) { z0[S] = zf; z1[S] = zf; lacc[S] = 0.f; }

    sh8 a0 = *(const sh8*)kp;
    sh8 a1 = *(const sh8*)(kp + 512);
    sh8 v0 = *(const sh8*)vp;
    sh8 v1 = *(const sh8*)(vp + 16*NN);

    for (int it = 0; it < 8; ++it) {
        const int nx = (it < 7) ? it + 1 : it;
        const short* kn = kp + (size_t)nx*1024;
        const short* vn = vp + (size_t)nx*32;
        sh8 na0 = *(const sh8*)kn;
        sh8 na1 = *(const sh8*)(kn + 512);
        sh8 nv0 = *(const sh8*)vn;
        sh8 nv1 = *(const sh8*)(vn + 16*NN);

        f4v s0[4], s1[4];
        #pragma unroll
        for (int S = 0; S < 4; ++S) {
            s0[S] = MFMA32(a0, qf[S], zf);
            s1[S] = MFMA32(a1, qf[S], zf);
        }

        sh8 p[4];
        #pragma unroll
        for (int S = 0; S < 4; ++S) {
            float e[8];
            #pragma unroll
            for (int r = 0; r < 4; ++r) {
                e[r]   = __builtin_amdgcn_exp2f(s0[S][r]);
                e[4+r] = __builtin_amdgcn_exp2f(s1[S][r]);
            }
            lacc[S] += ((e[0]+e[1])+(e[2]+e[3])) + ((e[4]+e[5])+(e[6]+e[7]));
            #pragma unroll
            for (int j = 0; j < 8; ++j) p[S][j] = f2b(e[j]);
        }

        #pragma unroll
        for (int S = 0; S < 4; ++S) {
            z0[S] = MFMA32(v0, p[S], z0[S]);   // d 0-15
            z1[S] = MFMA32(v1, p[S], z1[S]);   // d 16-31
        }

        a0 = na0; a1 = na1; v0 = nv0; v1 = nv1;
    }

    #pragma unroll
    for (int S = 0; S < 4; ++S) {
        lacc[S] += __shfl_xor(lacc[S], 16, 64);
        lacc[S] += __shfl_xor(lacc[S], 32, 64);
    }

    // stage 1: waves 8-15 write partials
    if (w >= 8) {
        #pragma unroll
        for (int S = 0; S < 4; ++S) {
            *(f4v*)&zr[w-8][S*16 + qi][4*g]      = z0[S];
            *(f4v*)&zr[w-8][S*16 + qi][16 + 4*g] = z1[S];
            if (g == 0) lr[w-8][S*16 + qi] = lacc[S];
        }
    }
    __syncthreads();
    // stage 2: waves 0-7 accumulate into the 8 slots
    if (w < 8) {
        #pragma unroll
        for (int S = 0; S < 4; ++S) {
            f4v ta = *(f4v*)&zr[w][S*16 + qi][4*g];
            f4v tb = *(f4v*)&zr[w][S*16 + qi][16 + 4*g];
            ta += z0[S]; tb += z1[S];
            *(f4v*)&zr[w][S*16 + qi][4*g]      = ta;
            *(f4v*)&zr[w][S*16 + qi][16 + 4*g] = tb;
            if (g == 0) lr[w][S*16 + qi] += lacc[S];
        }
    }
    __syncthreads();

    // stage 3: waves 0-3 finalize q-subtile w, project, residual, store
    if (w < 4) {
        const int q = w*16 + qi;
        float lm = 0.f;
        #pragma unroll
        for (int s = 0; s < 8; ++s) lm += lr[s][q];
        f4v zm0 = zf, zm1 = zf;
        #pragma unroll
        for (int s = 0; s < 8; ++s) {
            zm0 += *(f4v*)&zr[s][q][4*g];
            zm1 += *(f4v*)&zr[s][q][16 + 4*g];
        }
        const float inv = 1.f / lm;
        sh8 pz;
        #pragma unroll
        for (int r = 0; r < 4; ++r) {
            pz[r]   = f2b(zm0[r]*inv);
            pz[4+r] = f2b(zm1[r]*inv);
        }
        const int qcol = q0 + q;
        #pragma unroll
        for (int ct = 0; ct < 4; ++ct) {
            const float* wrow = wp + (ct*16 + qi)*HID;
            f4v wa = *(const f4v*)(wrow + 4*g);
            f4v wb = *(const f4v*)(wrow + 16 + 4*g);
            sh8 af;
            #pragma unroll
            for (int i = 0; i < 4; ++i) { af[i] = f2b(wa[i]); af[4+i] = f2b(wb[i]); }
            f4v cacc;
            #pragma unroll
            for (int r = 0; r < 4; ++r) {
                int c = ct*16 + 4*g + r;
                cacc[r] = x[((size_t)(b*CC + c))*NN + qcol] + bp[c];
            }
            cacc = MFMA32(af, pz, cacc);
            #pragma unroll
            for (int r = 0; r < 4; ++r) {
                int c = ct*16 + 4*g + r;
                out[((size_t)(b*CC + c))*NN + qcol] = cacc[r];
            }
        }
    }
}

extern "C" void kernel_launch(void* const* d_in, const int* in_sizes, int n_in,
                              void* d_out, int out_size, void* d_ws, size_t ws_size,
                              hipStream_t stream) {
    const float* x  = (const float*)d_in[0];
    const float* wq = (const float*)d_in[1];
    const float* bq = (const float*)d_in[2];
    const float* wk = (const float*)d_in[3];
    const float* bk = (const float*)d_in[4];
    const float* wv = (const float*)d_in[5];
    const float* bv = (const float*)d_in[6];
    const float* wp = (const float*)d_in[7];
    const float* bp = (const float*)d_in[8];

    short* Qw  = (short*)d_ws;                       // bf16 [B][N][HID], pre-scaled log2(e)
    short* Kw  = Qw + (size_t)BB*NN*HID;             // bf16 [B][N][HID]
    short* Vtp = Kw + (size_t)BB*NN*HID;             // bf16 [B][HID][N-permuted]

    qkv_kernel<<<dim3(256), dim3(1024), 0, stream>>>(x, wq, bq, wk, bk, wv, bv, Qw, Kw, Vtp);
    attn_kernel<<<dim3(256), dim3(1024), 0, stream>>>(Qw, Kw, Vtp, x, wp, bp, (float*)d_out);
}

// Round 8
// 30.075 us; speedup vs baseline: 2.1952x; 1.0020x over previous
//
#include <hip/hip_runtime.h>
#include <hip/hip_bf16.h>
#include <math.h>

#define BB 4
#define CC 64
#define HID 32
#define NN 4096
#define LOG2E 1.44269504088896f

typedef short sh2 __attribute__((ext_vector_type(2)));
typedef short sh8 __attribute__((ext_vector_type(8)));
typedef float f2v __attribute__((ext_vector_type(2)));
typedef float f4v __attribute__((ext_vector_type(4)));

#define MFMA32(A,B,C) __builtin_amdgcn_mfma_f32_16x16x32_bf16(A,B,C,0,0,0)

__device__ __forceinline__ short f2b(float f) {
    __hip_bfloat16 h = __float2bfloat16(f);
    union { __hip_bfloat16 hb; short s; } u; u.hb = h; return u.s;
}

// ---------------------------------------------------------------------------
// Kernel A: QKV projection -> bf16 Q[n][32] (pre-scaled by log2(e)),
// K[n][32], Vtp[32][n-permuted].  pos(key%32) = 8*((k>>2)&3)+(k&3)+4*(k>>4).
// Pad 84: ws-row bank stride 20 mod 32 -> 8 distinct bank-quads (was 2 at
// pad 80 = 16-way conflict on every b128 w-read).
// ---------------------------------------------------------------------------
__global__ __launch_bounds__(1024) void qkv_kernel(
    const float* __restrict__ x,
    const float* __restrict__ wq, const float* __restrict__ bq,
    const float* __restrict__ wk, const float* __restrict__ bk,
    const float* __restrict__ wv, const float* __restrict__ bv,
    short* __restrict__ Qw, short* __restrict__ Kw, short* __restrict__ Vtp)
{
    __shared__ float xs[64][84];
    __shared__ float ws[96][84];
    __shared__ float bs[96];

    const int t  = threadIdx.x;
    const int b  = blockIdx.x >> 6;
    const int n0 = (blockIdx.x & 63) << 6;

    {
        int c = t >> 4, j4 = (t & 15) << 2;
        *(f4v*)&xs[c][j4] = *(const f4v*)(x + ((size_t)(b*CC + c))*NN + n0 + j4);
    }
    #pragma unroll
    for (int kl = 0; kl < 2; ++kl) {
        int idx = t + 1024*kl;
        if (idx < 1536) {
            int r = idx >> 4, c4 = (idx & 15) << 2;
            const float* src = (r < 32) ? (wq + r*CC + c4)
                             : (r < 64) ? (wk + (r-32)*CC + c4)
                                        : (wv + (r-64)*CC + c4);
            *(f4v*)&ws[r][c4] = *(const f4v*)src;
        }
    }
    if (t < 96) bs[t] = (t < 32) ? bq[t] : (t < 64) ? bk[t-32] : bv[t-64];
    __syncthreads();

    const int hg = t & 31;
    const int j0 = (t >> 5) << 1;   // 2 spatial cols per thread

    float aq[2], ak[2], av[2];
    #pragma unroll
    for (int jj = 0; jj < 2; ++jj) { aq[jj]=bs[hg]; ak[jj]=bs[32+hg]; av[jj]=bs[64+hg]; }

    #pragma unroll
    for (int cs = 0; cs < 16; ++cs) {
        f4v wqv = *(f4v*)&ws[hg][cs*4];
        f4v wkv = *(f4v*)&ws[32+hg][cs*4];
        f4v wvv = *(f4v*)&ws[64+hg][cs*4];
        #pragma unroll
        for (int cc = 0; cc < 4; ++cc) {
            f2v xv = *(f2v*)&xs[cs*4+cc][j0];
            #pragma unroll
            for (int jj = 0; jj < 2; ++jj) {
                aq[jj] += wqv[cc]*xv[jj];
                ak[jj] += wkv[cc]*xv[jj];
                av[jj] += wvv[cc]*xv[jj];
            }
        }
    }

    const size_t nbase = (size_t)b*NN + n0 + j0;
    #pragma unroll
    for (int jj = 0; jj < 2; ++jj) {
        Qw[(nbase + jj)*HID + hg] = f2b(aq[jj] * LOG2E);  // exp2 trick
        Kw[(nbase + jj)*HID + hg] = f2b(ak[jj]);
    }
    const int w0  = j0 & 31;
    const int pos = 8*((w0 >> 2) & 3) + (w0 & 3) + 4*(w0 >> 4);
    sh2 vv; vv[0] = f2b(av[0]); vv[1] = f2b(av[1]);
    *(sh2*)(Vtp + ((size_t)b*HID + hg)*NN + n0 + (j0 & ~31) + pos) = vv;
}

// ---------------------------------------------------------------------------
// Kernel B: MFMA flash attention + projection + residual.  Single kernel.
// 256 blocks x 1024 thr (16 waves).  Block = 64 q; wave = 4 Q-frags x one
// key-sixteenth (256 keys, 8 iters of 32 keys).  4 waves/SIMD.
// 3-stage LDS merge: waves 8-15 write, 0-7 RMW, 0-3 finalize + project.
// ---------------------------------------------------------------------------
__global__ __launch_bounds__(1024, 4) void attn_kernel(
    const short* __restrict__ Qw, const short* __restrict__ Kw,
    const short* __restrict__ Vtp, const float* __restrict__ x,
    const float* __restrict__ wp, const float* __restrict__ bp,
    float* __restrict__ out)
{
    __shared__ float zr[8][64][33];   // [slot][q][d]  (67.6 KB)
    __shared__ float lr[8][64];

    const int t    = threadIdx.x;
    const int b    = blockIdx.x >> 6;
    const int q0   = (blockIdx.x & 63) << 6;
    const int lane = t & 63;
    const int w    = t >> 6;        // 0..15: key-sixteenth
    const int g    = lane >> 4;
    const int qi   = lane & 15;

    // 4 Q B-fragments, k-order dims 8g..8g+7
    sh8 qf[4];
    #pragma unroll
    for (int S = 0; S < 4; ++S)
        qf[S] = *(const sh8*)(Qw + ((size_t)b*NN + q0 + S*16 + qi)*HID + 8*g);

    const short* kp = Kw  + ((size_t)b*NN  + w*256 + qi)*HID + 8*g;
    const short* vp = Vtp + ((size_t)b*HID + qi)*NN + w*256 + 8*g;

    const f4v zf = {0.f,0.f,0.f,0.f};
    f4v z0[4], z1[4];
    float lacc[4];
    #pragma unroll
    for (int S = 0; S < 4; ++S) { z0[S] = zf; z1[S] = zf; lacc[S] = 0.f; }

    sh8 a0 = *(const sh8*)kp;
    sh8 a1 = *(const sh8*)(kp + 512);
    sh8 v0 = *(const sh8*)vp;
    sh8 v1 = *(const sh8*)(vp + 16*NN);

    for (int it = 0; it < 8; ++it) {
        const int nx = (it < 7) ? it + 1 : it;
        const short* kn = kp + (size_t)nx*1024;
        const short* vn = vp + (size_t)nx*32;
        sh8 na0 = *(const sh8*)kn;
        sh8 na1 = *(const sh8*)(kn + 512);
        sh8 nv0 = *(const sh8*)vn;
        sh8 nv1 = *(const sh8*)(vn + 16*NN);

        f4v s0[4], s1[4];
        #pragma unroll
        for (int S = 0; S < 4; ++S) {
            s0[S] = MFMA32(a0, qf[S], zf);
            s1[S] = MFMA32(a1, qf[S], zf);
        }

        sh8 p[4];
        #pragma unroll
        for (int S = 0; S < 4; ++S) {
            float e[8];
            #pragma unroll
            for (int r = 0; r < 4; ++r) {
                e[r]   = __builtin_amdgcn_exp2f(s0[S][r]);
                e[4+r] = __builtin_amdgcn_exp2f(s1[S][r]);
            }
            lacc[S] += ((e[0]+e[1])+(e[2]+e[3])) + ((e[4]+e[5])+(e[6]+e[7]));
            #pragma unroll
            for (int j = 0; j < 8; ++j) p[S][j] = f2b(e[j]);
        }

        #pragma unroll
        for (int S = 0; S < 4; ++S) {
            z0[S] = MFMA32(v0, p[S], z0[S]);   // d 0-15
            z1[S] = MFMA32(v1, p[S], z1[S]);   // d 16-31
        }

        a0 = na0; a1 = na1; v0 = nv0; v1 = nv1;
    }

    #pragma unroll
    for (int S = 0; S < 4; ++S) {
        lacc[S] += __shfl_xor(lacc[S], 16, 64);
        lacc[S] += __shfl_xor(lacc[S], 32, 64);
    }

    // stage 1: waves 8-15 write partials
    if (w >= 8) {
        #pragma unroll
        for (int S = 0; S < 4; ++S) {
            *(f4v*)&zr[w-8][S*16 + qi][4*g]      = z0[S];
            *(f4v*)&zr[w-8][S*16 + qi][16 + 4*g] = z1[S];
            if (g == 0) lr[w-8][S*16 + qi] = lacc[S];
        }
    }
    __syncthreads();
    // stage 2: waves 0-7 accumulate into the 8 slots
    if (w < 8) {
        #pragma unroll
        for (int S = 0; S < 4; ++S) {
            f4v ta = *(f4v*)&zr[w][S*16 + qi][4*g];
            f4v tb = *(f4v*)&zr[w][S*16 + qi][16 + 4*g];
            ta += z0[S]; tb += z1[S];
            *(f4v*)&zr[w][S*16 + qi][4*g]      = ta;
            *(f4v*)&zr[w][S*16 + qi][16 + 4*g] = tb;
            if (g == 0) lr[w][S*16 + qi] += lacc[S];
        }
    }
    __syncthreads();

    // stage 3: waves 0-3 finalize q-subtile w, project, residual, store
    if (w < 4) {
        const int q = w*16 + qi;
        float lm = 0.f;
        #pragma unroll
        for (int s = 0; s < 8; ++s) lm += lr[s][q];
        f4v zm0 = zf, zm1 = zf;
        #pragma unroll
        for (int s = 0; s < 8; ++s) {
            zm0 += *(f4v*)&zr[s][q][4*g];
            zm1 += *(f4v*)&zr[s][q][16 + 4*g];
        }
        const float inv = 1.f / lm;
        sh8 pz;
        #pragma unroll
        for (int r = 0; r < 4; ++r) {
            pz[r]   = f2b(zm0[r]*inv);
            pz[4+r] = f2b(zm1[r]*inv);
        }
        const int qcol = q0 + q;
        #pragma unroll
        for (int ct = 0; ct < 4; ++ct) {
            const float* wrow = wp + (ct*16 + qi)*HID;
            f4v wa = *(const f4v*)(wrow + 4*g);
            f4v wb = *(const f4v*)(wrow + 16 + 4*g);
            sh8 af;
            #pragma unroll
            for (int i = 0; i < 4; ++i) { af[i] = f2b(wa[i]); af[4+i] = f2b(wb[i]); }
            f4v cacc;
            #pragma unroll
            for (int r = 0; r < 4; ++r) {
                int c = ct*16 + 4*g + r;
                cacc[r] = x[((size_t)(b*CC + c))*NN + qcol] + bp[c];
            }
            cacc = MFMA32(af, pz, cacc);
            #pragma unroll
            for (int r = 0; r < 4; ++r) {
                int c = ct*16 + 4*g + r;
                out[((size_t)(b*CC + c))*NN + qcol] = cacc[r];
            }
        }
    }
}

extern "C" void kernel_launch(void* const* d_in, const int* in_sizes, int n_in,
                              void* d_out, int out_size, void* d_ws, size_t ws_size,
                              hipStream_t stream) {
    const float* x  = (const float*)d_in[0];
    const float* wq = (const float*)d_in[1];
    const float* bq = (const float*)d_in[2];
    const float* wk = (const float*)d_in[3];
    const float* bk = (const float*)d_in[4];
    const float* wv = (const float*)d_in[5];
    const float* bv = (const float*)d_in[6];
    const float* wp = (const float*)d_in[7];
    const float* bp = (const float*)d_in[8];

    short* Qw  = (short*)d_ws;                       // bf16 [B][N][HID], pre-scaled log2(e)
    short* Kw  = Qw + (size_t)BB*NN*HID;             // bf16 [B][N][HID]
    short* Vtp = Kw + (size_t)BB*NN*HID;             // bf16 [B][HID][N-permuted]

    qkv_kernel<<<dim3(256), dim3(1024), 0, stream>>>(x, wq, bq, wk, bk, wv, bv, Qw, Kw, Vtp);
    attn_kernel<<<dim3(256), dim3(1024), 0, stream>>>(Qw, Kw, Vtp, x, wp, bp, (float*)d_out);
}